// Round 1
// baseline (853.033 us; speedup 1.0000x reference)
//
#include <hip/hip_runtime.h>

#define N_NODES 50000
#define N_EDGES 800000
#define D 128          // D_IN == D_OUT == 128

// ---------------------------------------------------------------------------
// Kernel 1: out[n][d] = bias[d]   (d_out is poisoned 0xAA before every call)
// ---------------------------------------------------------------------------
__global__ void gc_init_out(const float* __restrict__ bias,
                            float* __restrict__ out) {
    const int total4 = N_NODES * D / 4;                // 1.6M float4
    const float4* b4 = (const float4*)bias;            // 32 float4 per row
    float4* o4 = (float4*)out;
    for (int i = blockIdx.x * blockDim.x + threadIdx.x; i < total4;
         i += gridDim.x * blockDim.x) {
        o4[i] = b4[i & 31];
    }
}

// ---------------------------------------------------------------------------
// Kernel 2: S = X @ W   [50000,128] x [128,128], fp32 vector ALU
// Each thread computes 4 consecutive output cols for one row.
// idx = row*32 + colgroup. Lanes 0..31 share a row -> X loads broadcast,
// W loads are coalesced float4 (W is 64 KB, L1/L2 resident).
// ---------------------------------------------------------------------------
__global__ void gc_gemm(const float* __restrict__ X,
                        const float* __restrict__ W,
                        float* __restrict__ S) {
    int idx = blockIdx.x * blockDim.x + threadIdx.x;
    int row = idx >> 5;
    int cg  = idx & 31;
    if (row >= N_NODES) return;

    const float4* W4 = (const float4*)W;        // W4[k*32 + cg]
    const float4* x4 = (const float4*)(X + row * D);

    float4 acc = {0.f, 0.f, 0.f, 0.f};
    #pragma unroll
    for (int k4 = 0; k4 < D / 4; ++k4) {
        float4 xv = x4[k4];
        float4 w0 = W4[(k4 * 4 + 0) * 32 + cg];
        float4 w1 = W4[(k4 * 4 + 1) * 32 + cg];
        float4 w2 = W4[(k4 * 4 + 2) * 32 + cg];
        float4 w3 = W4[(k4 * 4 + 3) * 32 + cg];
        acc.x += xv.x * w0.x; acc.y += xv.x * w0.y; acc.z += xv.x * w0.z; acc.w += xv.x * w0.w;
        acc.x += xv.y * w1.x; acc.y += xv.y * w1.y; acc.z += xv.y * w1.z; acc.w += xv.y * w1.w;
        acc.x += xv.z * w2.x; acc.y += xv.z * w2.y; acc.z += xv.z * w2.z; acc.w += xv.z * w2.w;
        acc.x += xv.w * w3.x; acc.y += xv.w * w3.y; acc.z += xv.w * w3.z; acc.w += xv.w * w3.w;
    }
    ((float4*)S)[idx] = acc;
}

// ---------------------------------------------------------------------------
// Kernel 3: scatter — one wave per edge, lane handles 2 consecutive floats.
// out[row*128 + 2*lane + {0,1}] += val * S[col*128 + 2*lane + {0,1}]
// unsafeAtomicAdd -> hardware global_atomic_add_f32 (no CAS loop).
// ---------------------------------------------------------------------------
__global__ void gc_scatter(const float* __restrict__ S,
                           const float* __restrict__ ev,
                           const int* __restrict__ er,
                           const int* __restrict__ ec,
                           float* __restrict__ out) {
    int gtid = blockIdx.x * blockDim.x + threadIdx.x;
    int edge = gtid >> 6;
    int lane = threadIdx.x & 63;
    if (edge >= N_EDGES) return;

    float v = ev[edge];
    int   r = er[edge];
    int   c = ec[edge];

    const float2* s2 = (const float2*)(S + (size_t)c * D);
    float2 sv = s2[lane];

    float* dst = out + (size_t)r * D + lane * 2;
    unsafeAtomicAdd(dst + 0, v * sv.x);
    unsafeAtomicAdd(dst + 1, v * sv.y);
}

// ---------------------------------------------------------------------------
extern "C" void kernel_launch(void* const* d_in, const int* in_sizes, int n_in,
                              void* d_out, int out_size, void* d_ws, size_t ws_size,
                              hipStream_t stream) {
    const float* X    = (const float*)d_in[0];   // [50000,128]
    const float* W    = (const float*)d_in[1];   // [128,128]
    const float* bias = (const float*)d_in[2];   // [128]
    const float* ev   = (const float*)d_in[3];   // [800000]
    const int*   er   = (const int*)  d_in[4];   // [800000]
    const int*   ec   = (const int*)  d_in[5];   // [800000]
    float* out = (float*)d_out;                  // [50000,128]
    float* S   = (float*)d_ws;                   // [50000,128] scratch, 25.6 MB

    // 1) out = bias (broadcast rows)
    gc_init_out<<<2048, 256, 0, stream>>>(bias, out);

    // 2) S = X @ W
    {
        int total = N_NODES * 32;                // one thread per 4 output cols
        int blocks = (total + 255) / 256;
        gc_gemm<<<blocks, 256, 0, stream>>>(X, W, S);
    }

    // 3) atomic scatter over edges (one wave per edge)
    {
        long long total = (long long)N_EDGES * 64;
        int blocks = (int)((total + 255) / 256);
        gc_scatter<<<blocks, 256, 0, stream>>>(S, ev, er, ec, out);
    }
}

// Round 3
// 460.242 us; speedup vs baseline: 1.8534x; 1.8534x over previous
//
#include <hip/hip_runtime.h>

#define N_NODES 50000
#define N_EDGES 800000
#define D 128          // D_IN == D_OUT == 128

// Workspace layout (bytes):
#define S_OFF      0u            // S = X@W, fp32 [50000][128] = 25,600,000 B
#define COUNTS_OFF 25600000u     // int[50000]
#define OFFS_OFF   25900000u     // int[50001] row offsets
#define CURSOR_OFF 26200000u     // int[50000] fill cursors
#define CSR_OFF    26500000u     // int2[800000]  (col, val-bits) = 6,400,000 B
#define WS_NEEDED  (CSR_OFF + (size_t)N_EDGES * 8u)   // 32,900,000 B

// ---------------------------------------------------------------------------
// GEMM: S = X @ W   [50000,128] x [128,128], fp32 vector ALU.
// One thread computes 4 consecutive output cols of one row.
// ---------------------------------------------------------------------------
__global__ void gc_gemm(const float* __restrict__ X,
                        const float* __restrict__ W,
                        float* __restrict__ S) {
    int idx = blockIdx.x * blockDim.x + threadIdx.x;
    int row = idx >> 5;
    int cg  = idx & 31;
    if (row >= N_NODES) return;

    const float4* W4 = (const float4*)W;
    const float4* x4 = (const float4*)(X + row * D);

    float4 acc = {0.f, 0.f, 0.f, 0.f};
    #pragma unroll
    for (int k4 = 0; k4 < D / 4; ++k4) {
        float4 xv = x4[k4];
        float4 w0 = W4[(k4 * 4 + 0) * 32 + cg];
        float4 w1 = W4[(k4 * 4 + 1) * 32 + cg];
        float4 w2 = W4[(k4 * 4 + 2) * 32 + cg];
        float4 w3 = W4[(k4 * 4 + 3) * 32 + cg];
        acc.x += xv.x * w0.x; acc.y += xv.x * w0.y; acc.z += xv.x * w0.z; acc.w += xv.x * w0.w;
        acc.x += xv.y * w1.x; acc.y += xv.y * w1.y; acc.z += xv.y * w1.z; acc.w += xv.y * w1.w;
        acc.x += xv.z * w2.x; acc.y += xv.z * w2.y; acc.z += xv.z * w2.z; acc.w += xv.z * w2.w;
        acc.x += xv.w * w3.x; acc.y += xv.w * w3.y; acc.z += xv.w * w3.z; acc.w += xv.w * w3.w;
    }
    ((float4*)S)[idx] = acc;
}

// ---------------------------------------------------------------------------
// CSR build step 1: histogram of edge rows.  counts must be pre-zeroed.
// ---------------------------------------------------------------------------
__global__ void gc_hist(const int* __restrict__ er, int* __restrict__ counts) {
    int e = blockIdx.x * blockDim.x + threadIdx.x;
    if (e < N_EDGES) atomicAdd(&counts[er[e]], 1);
}

// ---------------------------------------------------------------------------
// CSR build step 2: single-block exclusive scan over 50000 counts.
// Each thread serially sums a 49-element chunk; LDS scan over 1024 partials.
// ---------------------------------------------------------------------------
__global__ __launch_bounds__(1024) void gc_scan(const int* __restrict__ counts,
                                                int* __restrict__ offsets,
                                                int* __restrict__ cursor) {
    __shared__ int partial[1024];
    const int t  = threadIdx.x;
    const int CH = (N_NODES + 1023) / 1024;   // 49
    const int base = t * CH;

    int sum = 0;
    for (int i = 0; i < CH; ++i) {
        int idx = base + i;
        if (idx < N_NODES) sum += counts[idx];
    }
    partial[t] = sum;
    __syncthreads();
    for (int off = 1; off < 1024; off <<= 1) {
        int v = (t >= off) ? partial[t - off] : 0;
        __syncthreads();
        partial[t] += v;
        __syncthreads();
    }
    int excl = (t == 0) ? 0 : partial[t - 1];
    for (int i = 0; i < CH; ++i) {
        int idx = base + i;
        if (idx < N_NODES) {
            offsets[idx] = excl;
            cursor[idx]  = excl;
            excl += counts[idx];
        }
    }
    if (t == 1023) offsets[N_NODES] = excl;   // == N_EDGES
}

// ---------------------------------------------------------------------------
// CSR build step 3: scatter (col, val) pairs into row-sorted slots.
// ---------------------------------------------------------------------------
__global__ void gc_fill(const int* __restrict__ er, const int* __restrict__ ec,
                        const float* __restrict__ ev, int* __restrict__ cursor,
                        int2* __restrict__ csr) {
    int e = blockIdx.x * blockDim.x + threadIdx.x;
    if (e >= N_EDGES) return;
    int pos = atomicAdd(&cursor[er[e]], 1);
    csr[pos] = make_int2(ec[e], __float_as_int(ev[e]));
}

// ---------------------------------------------------------------------------
// Gather: one wave per output row, lane owns a float2 (128 floats / 64 lanes).
// out[row] = bias + sum_e val_e * S[col_e].   No fp32 atomics anywhere.
// ---------------------------------------------------------------------------
__global__ void gc_gather(const float* __restrict__ S,
                          const int* __restrict__ offsets,
                          const int2* __restrict__ csr,
                          const float* __restrict__ bias,
                          float* __restrict__ out) {
    int wid  = (blockIdx.x * blockDim.x + threadIdx.x) >> 6;
    int lane = threadIdx.x & 63;
    if (wid >= N_NODES) return;

    int start = offsets[wid];
    int end   = offsets[wid + 1];

    float2 acc = {0.f, 0.f};
    int e = start;
    // unroll-by-2: issue both edge descriptors, then both S reads
    for (; e + 1 < end; e += 2) {
        int2 cv0 = csr[e];
        int2 cv1 = csr[e + 1];
        float2 s0 = *(const float2*)(S + (size_t)cv0.x * D + lane * 2);
        float2 s1 = *(const float2*)(S + (size_t)cv1.x * D + lane * 2);
        float v0 = __int_as_float(cv0.y);
        float v1 = __int_as_float(cv1.y);
        acc.x += v0 * s0.x; acc.y += v0 * s0.y;
        acc.x += v1 * s1.x; acc.y += v1 * s1.y;
    }
    if (e < end) {
        int2 cv = csr[e];
        float2 s = *(const float2*)(S + (size_t)cv.x * D + lane * 2);
        float v = __int_as_float(cv.y);
        acc.x += v * s.x; acc.y += v * s.y;
    }

    float2 b = *(const float2*)(bias + lane * 2);
    *(float2*)(out + (size_t)wid * D + lane * 2) = make_float2(acc.x + b.x, acc.y + b.y);
}

// ---------------------------------------------------------------------------
// Fallback path (ws too small for CSR): round-1 atomic scatter.
// ---------------------------------------------------------------------------
__global__ void gc_init_out(const float* __restrict__ bias,
                            float* __restrict__ out) {
    const int total4 = N_NODES * D / 4;
    const float4* b4 = (const float4*)bias;
    float4* o4 = (float4*)out;
    for (int i = blockIdx.x * blockDim.x + threadIdx.x; i < total4;
         i += gridDim.x * blockDim.x) {
        o4[i] = b4[i & 31];
    }
}

__global__ void gc_scatter(const float* __restrict__ S,
                           const float* __restrict__ ev,
                           const int* __restrict__ er,
                           const int* __restrict__ ec,
                           float* __restrict__ out) {
    int gtid = blockIdx.x * blockDim.x + threadIdx.x;
    int edge = gtid >> 6;
    int lane = threadIdx.x & 63;
    if (edge >= N_EDGES) return;

    float v = ev[edge];
    int   r = er[edge];
    int   c = ec[edge];

    const float2* s2 = (const float2*)(S + (size_t)c * D);
    float2 sv = s2[lane];

    float* dst = out + (size_t)r * D + lane * 2;
    unsafeAtomicAdd(dst + 0, v * sv.x);
    unsafeAtomicAdd(dst + 1, v * sv.y);
}

// ---------------------------------------------------------------------------
extern "C" void kernel_launch(void* const* d_in, const int* in_sizes, int n_in,
                              void* d_out, int out_size, void* d_ws, size_t ws_size,
                              hipStream_t stream) {
    const float* X    = (const float*)d_in[0];
    const float* W    = (const float*)d_in[1];
    const float* bias = (const float*)d_in[2];
    const float* ev   = (const float*)d_in[3];
    const int*   er   = (const int*)  d_in[4];
    const int*   ec   = (const int*)  d_in[5];
    float* out = (float*)d_out;

    char* ws = (char*)d_ws;
    float* S = (float*)(ws + S_OFF);

    // GEMM first (independent of CSR build; both paths need S)
    {
        int total = N_NODES * 32;
        int blocks = (total + 255) / 256;
        gc_gemm<<<blocks, 256, 0, stream>>>(X, W, S);
    }

    if (ws_size >= WS_NEEDED) {
        int*  counts  = (int*)(ws + COUNTS_OFF);
        int*  offsets = (int*)(ws + OFFS_OFF);
        int*  cursor  = (int*)(ws + CURSOR_OFF);
        int2* csr     = (int2*)(ws + CSR_OFF);

        hipMemsetAsync(counts, 0, N_NODES * sizeof(int), stream);

        int eblocks = (N_EDGES + 255) / 256;
        gc_hist<<<eblocks, 256, 0, stream>>>(er, counts);
        gc_scan<<<1, 1024, 0, stream>>>(counts, offsets, cursor);
        gc_fill<<<eblocks, 256, 0, stream>>>(er, ec, ev, cursor, csr);

        // one wave per row: 50000 waves, 4 waves / 256-thread block
        int gblocks = (N_NODES * 64 + 255) / 256;
        gc_gather<<<gblocks, 256, 0, stream>>>(S, offsets, csr, bias, out);
    } else {
        // fallback: atomic scatter (round-1 path)
        gc_init_out<<<2048, 256, 0, stream>>>(bias, out);
        long long total = (long long)N_EDGES * 64;
        int blocks = (int)((total + 255) / 256);
        gc_scatter<<<blocks, 256, 0, stream>>>(S, ev, er, ec, out);
    }
}

// Round 5
// 270.184 us; speedup vs baseline: 3.1572x; 1.7034x over previous
//
#include <hip/hip_runtime.h>

#define N_NODES 50000
#define N_EDGES 800000
#define D 128          // D_IN == D_OUT == 128

// Workspace layout (bytes):
#define S_OFF      0u            // S = X@W, fp32 [50000][128] = 25,600,000 B
#define COUNTS_OFF 25600000u     // int[50000]
#define OFFS_OFF   25800000u     // int[50001]
#define CURSOR_OFF 26000008u     // int[50000]
#define EXCL_OFF   26200008u     // int[50000]  block-local exclusive scan
#define BSUM_OFF   26400008u     // int[256]    per-block sums
#define BPRE_OFF   26401032u     // int[256]    scanned block sums
#define CSR_OFF    26402064u     // int2[800000] = 6,400,000 B (8B aligned)
#define WS_NEEDED  (CSR_OFF + (size_t)N_EDGES * 8u)   // 32,802,064 B

#define SCAN_NBLK ((N_NODES + 255) / 256)   // 196

// ---------------------------------------------------------------------------
// GEMM: S = X @ W.  512-thread blocks, 64 rows/block, full W staged in LDS
// (64 KB -> 2 blocks/CU, 16 waves/CU).  Thread = 4 rows x 4 cols tile.
// W LDS traffic: 0.8 GB @ 69 TB/s ~ 12 us; VALU floor 10.4 us.
// ---------------------------------------------------------------------------
__global__ __launch_bounds__(512) void gc_gemm(const float* __restrict__ X,
                                               const float* __restrict__ W,
                                               float* __restrict__ S) {
    __shared__ float4 LW[4096];              // LW[k*32 + cg] = W[k][4cg..4cg+3]
    const int t = threadIdx.x;
    const float4* W4 = (const float4*)W;
    #pragma unroll
    for (int i = 0; i < 8; ++i) LW[t + i * 512] = W4[t + i * 512];
    __syncthreads();

    const int rg = t >> 5;                   // 0..15
    const int cg = t & 31;                   // 4-col group
    const int row0 = blockIdx.x * 64 + rg * 4;
    if (row0 >= N_NODES) return;             // 50000 % 4 == 0 -> all-or-nothing

    const float4* x0 = (const float4*)(X + (size_t)(row0 + 0) * D);
    const float4* x1 = (const float4*)(X + (size_t)(row0 + 1) * D);
    const float4* x2 = (const float4*)(X + (size_t)(row0 + 2) * D);
    const float4* x3 = (const float4*)(X + (size_t)(row0 + 3) * D);

    float4 a0 = {0.f,0.f,0.f,0.f}, a1 = a0, a2 = a0, a3 = a0;

    #pragma unroll 4
    for (int k4 = 0; k4 < 32; ++k4) {
        float4 xv0 = x0[k4], xv1 = x1[k4], xv2 = x2[k4], xv3 = x3[k4];
        const float* xs0 = (const float*)&xv0;
        const float* xs1 = (const float*)&xv1;
        const float* xs2 = (const float*)&xv2;
        const float* xs3 = (const float*)&xv3;
        #pragma unroll
        for (int kk = 0; kk < 4; ++kk) {
            float4 wv = LW[(k4 * 4 + kk) * 32 + cg];
            float s0 = xs0[kk], s1 = xs1[kk], s2 = xs2[kk], s3 = xs3[kk];
            a0.x += s0 * wv.x; a0.y += s0 * wv.y; a0.z += s0 * wv.z; a0.w += s0 * wv.w;
            a1.x += s1 * wv.x; a1.y += s1 * wv.y; a1.z += s1 * wv.z; a1.w += s1 * wv.w;
            a2.x += s2 * wv.x; a2.y += s2 * wv.y; a2.z += s2 * wv.z; a2.w += s2 * wv.w;
            a3.x += s3 * wv.x; a3.y += s3 * wv.y; a3.z += s3 * wv.z; a3.w += s3 * wv.w;
        }
    }
    float4* S4 = (float4*)S;
    S4[(size_t)(row0 + 0) * 32 + cg] = a0;
    S4[(size_t)(row0 + 1) * 32 + cg] = a1;
    S4[(size_t)(row0 + 2) * 32 + cg] = a2;
    S4[(size_t)(row0 + 3) * 32 + cg] = a3;
}

// ---------------------------------------------------------------------------
// CSR build step 1: histogram of edge rows (counts pre-zeroed).
// ---------------------------------------------------------------------------
__global__ void gc_hist(const int* __restrict__ er, int* __restrict__ counts) {
    int e = blockIdx.x * blockDim.x + threadIdx.x;
    if (e < N_EDGES) atomicAdd(&counts[er[e]], 1);
}

// ---------------------------------------------------------------------------
// Two-level scan.  A: per-block (256-wide, coalesced) local exclusive scan +
// block sum.  B: single block scans the 196 block sums.  C: add-back.
// ---------------------------------------------------------------------------
__global__ __launch_bounds__(256) void gc_scan_a(const int* __restrict__ counts,
                                                 int* __restrict__ excl,
                                                 int* __restrict__ bsum) {
    __shared__ int sm[256];
    const int t = threadIdx.x;
    const int i = blockIdx.x * 256 + t;
    int c = (i < N_NODES) ? counts[i] : 0;
    sm[t] = c;
    __syncthreads();
    #pragma unroll
    for (int off = 1; off < 256; off <<= 1) {
        int v = (t >= off) ? sm[t - off] : 0;
        __syncthreads();
        sm[t] += v;
        __syncthreads();
    }
    if (i < N_NODES) excl[i] = sm[t] - c;        // exclusive within block
    if (t == 255) bsum[blockIdx.x] = sm[255];    // block total
}

__global__ __launch_bounds__(256) void gc_scan_b(const int* __restrict__ bsum,
                                                 int* __restrict__ bpre) {
    __shared__ int sm[256];
    const int t = threadIdx.x;
    int v = (t < SCAN_NBLK) ? bsum[t] : 0;
    sm[t] = v;
    __syncthreads();
    #pragma unroll
    for (int off = 1; off < 256; off <<= 1) {
        int x = (t >= off) ? sm[t - off] : 0;
        __syncthreads();
        sm[t] += x;
        __syncthreads();
    }
    if (t < SCAN_NBLK) bpre[t] = sm[t] - v;      // exclusive block prefix
}

__global__ __launch_bounds__(256) void gc_scan_c(const int* __restrict__ excl,
                                                 const int* __restrict__ bpre,
                                                 int* __restrict__ offsets,
                                                 int* __restrict__ cursor) {
    const int i = blockIdx.x * 256 + threadIdx.x;
    if (i < N_NODES) {
        int o = excl[i] + bpre[blockIdx.x];
        offsets[i] = o;
        cursor[i]  = o;
    }
    if (i == 0) offsets[N_NODES] = N_EDGES;
}

// ---------------------------------------------------------------------------
// CSR build step 3: scatter (col, val) pairs into row-sorted slots.
// ---------------------------------------------------------------------------
__global__ void gc_fill(const int* __restrict__ er, const int* __restrict__ ec,
                        const float* __restrict__ ev, int* __restrict__ cursor,
                        int2* __restrict__ csr) {
    int e = blockIdx.x * blockDim.x + threadIdx.x;
    if (e >= N_EDGES) return;
    int pos = atomicAdd(&cursor[er[e]], 1);
    csr[pos] = make_int2(ec[e], __float_as_int(ev[e]));
}

// ---------------------------------------------------------------------------
// Gather: one wave per output row, lane owns a float2.  Unroll x4 for MLP.
// out[row] = bias + sum_e val_e * S[col_e].   No fp32 atomics anywhere.
// ---------------------------------------------------------------------------
__global__ void gc_gather(const float* __restrict__ S,
                          const int* __restrict__ offsets,
                          const int2* __restrict__ csr,
                          const float* __restrict__ bias,
                          float* __restrict__ out) {
    int wid  = (blockIdx.x * blockDim.x + threadIdx.x) >> 6;
    int lane = threadIdx.x & 63;
    if (wid >= N_NODES) return;

    int start = offsets[wid];
    int end   = offsets[wid + 1];

    float2 acc = {0.f, 0.f};
    int e = start;
    for (; e + 3 < end; e += 4) {
        int2 cv0 = csr[e];
        int2 cv1 = csr[e + 1];
        int2 cv2 = csr[e + 2];
        int2 cv3 = csr[e + 3];
        float2 s0 = *(const float2*)(S + (size_t)cv0.x * D + lane * 2);
        float2 s1 = *(const float2*)(S + (size_t)cv1.x * D + lane * 2);
        float2 s2 = *(const float2*)(S + (size_t)cv2.x * D + lane * 2);
        float2 s3 = *(const float2*)(S + (size_t)cv3.x * D + lane * 2);
        float v0 = __int_as_float(cv0.y);
        float v1 = __int_as_float(cv1.y);
        float v2 = __int_as_float(cv2.y);
        float v3 = __int_as_float(cv3.y);
        acc.x += v0 * s0.x; acc.y += v0 * s0.y;
        acc.x += v1 * s1.x; acc.y += v1 * s1.y;
        acc.x += v2 * s2.x; acc.y += v2 * s2.y;
        acc.x += v3 * s3.x; acc.y += v3 * s3.y;
    }
    for (; e < end; ++e) {
        int2 cv = csr[e];
        float2 s = *(const float2*)(S + (size_t)cv.x * D + lane * 2);
        float v = __int_as_float(cv.y);
        acc.x += v * s.x; acc.y += v * s.y;
    }

    float2 b = *(const float2*)(bias + lane * 2);
    *(float2*)(out + (size_t)wid * D + lane * 2) = make_float2(acc.x + b.x, acc.y + b.y);
}

// ---------------------------------------------------------------------------
// Fallback path (ws too small for CSR): atomic scatter.
// ---------------------------------------------------------------------------
__global__ void gc_init_out(const float* __restrict__ bias,
                            float* __restrict__ out) {
    const int total4 = N_NODES * D / 4;
    const float4* b4 = (const float4*)bias;
    float4* o4 = (float4*)out;
    for (int i = blockIdx.x * blockDim.x + threadIdx.x; i < total4;
         i += gridDim.x * blockDim.x) {
        o4[i] = b4[i & 31];
    }
}

__global__ void gc_scatter(const float* __restrict__ S,
                           const float* __restrict__ ev,
                           const int* __restrict__ er,
                           const int* __restrict__ ec,
                           float* __restrict__ out) {
    int gtid = blockIdx.x * blockDim.x + threadIdx.x;
    int edge = gtid >> 6;
    int lane = threadIdx.x & 63;
    if (edge >= N_EDGES) return;

    float v = ev[edge];
    int   r = er[edge];
    int   c = ec[edge];

    const float2* s2 = (const float2*)(S + (size_t)c * D);
    float2 sv = s2[lane];

    float* dst = out + (size_t)r * D + lane * 2;
    unsafeAtomicAdd(dst + 0, v * sv.x);
    unsafeAtomicAdd(dst + 1, v * sv.y);
}

// ---------------------------------------------------------------------------
extern "C" void kernel_launch(void* const* d_in, const int* in_sizes, int n_in,
                              void* d_out, int out_size, void* d_ws, size_t ws_size,
                              hipStream_t stream) {
    const float* X    = (const float*)d_in[0];
    const float* W    = (const float*)d_in[1];
    const float* bias = (const float*)d_in[2];
    const float* ev   = (const float*)d_in[3];
    const int*   er   = (const int*)  d_in[4];
    const int*   ec   = (const int*)  d_in[5];
    float* out = (float*)d_out;

    char* ws = (char*)d_ws;
    float* S = (float*)(ws + S_OFF);

    // GEMM (64 rows / 512-thread block)
    gc_gemm<<<(N_NODES + 63) / 64, 512, 0, stream>>>(X, W, S);

    if (ws_size >= WS_NEEDED) {
        int*  counts  = (int*)(ws + COUNTS_OFF);
        int*  offsets = (int*)(ws + OFFS_OFF);
        int*  cursor  = (int*)(ws + CURSOR_OFF);
        int*  excl    = (int*)(ws + EXCL_OFF);
        int*  bsum    = (int*)(ws + BSUM_OFF);
        int*  bpre    = (int*)(ws + BPRE_OFF);
        int2* csr     = (int2*)(ws + CSR_OFF);

        hipMemsetAsync(counts, 0, N_NODES * sizeof(int), stream);

        int eblocks = (N_EDGES + 255) / 256;
        gc_hist<<<eblocks, 256, 0, stream>>>(er, counts);
        gc_scan_a<<<SCAN_NBLK, 256, 0, stream>>>(counts, excl, bsum);
        gc_scan_b<<<1, 256, 0, stream>>>(bsum, bpre);
        gc_scan_c<<<SCAN_NBLK, 256, 0, stream>>>(excl, bpre, offsets, cursor);
        gc_fill<<<eblocks, 256, 0, stream>>>(er, ec, ev, cursor, csr);

        // one wave per row: 50000 waves, 4 waves / 256-thread block
        int gblocks = (N_NODES * 64 + 255) / 256;
        gc_gather<<<gblocks, 256, 0, stream>>>(S, offsets, csr, bias, out);
    } else {
        // fallback: atomic scatter
        gc_init_out<<<2048, 256, 0, stream>>>(bias, out);
        long long total = (long long)N_EDGES * 64;
        int blocks = (int)((total + 255) / 256);
        gc_scatter<<<blocks, 256, 0, stream>>>(S, ev, er, ec, out);
    }
}

// Round 6
// 249.345 us; speedup vs baseline: 3.4211x; 1.0836x over previous
//
#include <hip/hip_runtime.h>

#define N_NODES 50000
#define N_EDGES 800000
#define D 128          // D_IN == D_OUT == 128

// Workspace layout (bytes):
#define S_OFF      0u            // S = X@W, bf16 [50000][128] = 12,800,000 B
#define COUNTS_OFF 12800000u     // int[50000]
#define OFFS_OFF   13000000u     // int[50001]
#define CURSOR_OFF 13200008u     // int[50000]
#define EXCL_OFF   13400008u     // int[50000]
#define BSUM_OFF   13600008u     // int[256]
#define BPRE_OFF   13601032u     // int[256]
#define CSR_OFF    13602064u     // uint[800000] packed (col<<16 | bf16(val)) = 3,200,000 B
#define WS_NEEDED  (CSR_OFF + (size_t)N_EDGES * 4u)   // 16,802,064 B

#define SCAN_NBLK ((N_NODES + 255) / 256)   // 196

__device__ __forceinline__ unsigned bf16_rne(float f) {
    unsigned u = __float_as_uint(f);
    return (u + 0x7fffu + ((u >> 16) & 1u)) >> 16;
}

// ---------------------------------------------------------------------------
// GEMM: S = X @ W, fp32 math, bf16 output.  512-thread blocks, 64 rows/block,
// full W (64 KB fp32) staged in LDS.  Thread = 4 rows x 4 cols tile.
// ---------------------------------------------------------------------------
__global__ __launch_bounds__(512) void gc_gemm(const float* __restrict__ X,
                                               const float* __restrict__ W,
                                               unsigned* __restrict__ Sb) {
    __shared__ float4 LW[4096];              // LW[k*32 + cg] = W[k][4cg..4cg+3]
    const int t = threadIdx.x;
    const float4* W4 = (const float4*)W;
    #pragma unroll
    for (int i = 0; i < 8; ++i) LW[t + i * 512] = W4[t + i * 512];
    __syncthreads();

    const int rg = t >> 5;                   // 0..15
    const int cg = t & 31;                   // 4-col group
    const int row0 = blockIdx.x * 64 + rg * 4;
    if (row0 >= N_NODES) return;             // 50000 % 4 == 0

    const float4* x0 = (const float4*)(X + (size_t)(row0 + 0) * D);
    const float4* x1 = (const float4*)(X + (size_t)(row0 + 1) * D);
    const float4* x2 = (const float4*)(X + (size_t)(row0 + 2) * D);
    const float4* x3 = (const float4*)(X + (size_t)(row0 + 3) * D);

    float4 a0 = {0.f,0.f,0.f,0.f}, a1 = a0, a2 = a0, a3 = a0;

    #pragma unroll 4
    for (int k4 = 0; k4 < 32; ++k4) {
        float4 xv0 = x0[k4], xv1 = x1[k4], xv2 = x2[k4], xv3 = x3[k4];
        const float* xs0 = (const float*)&xv0;
        const float* xs1 = (const float*)&xv1;
        const float* xs2 = (const float*)&xv2;
        const float* xs3 = (const float*)&xv3;
        #pragma unroll
        for (int kk = 0; kk < 4; ++kk) {
            float4 wv = LW[(k4 * 4 + kk) * 32 + cg];
            float s0 = xs0[kk], s1 = xs1[kk], s2 = xs2[kk], s3 = xs3[kk];
            a0.x += s0 * wv.x; a0.y += s0 * wv.y; a0.z += s0 * wv.z; a0.w += s0 * wv.w;
            a1.x += s1 * wv.x; a1.y += s1 * wv.y; a1.z += s1 * wv.z; a1.w += s1 * wv.w;
            a2.x += s2 * wv.x; a2.y += s2 * wv.y; a2.z += s2 * wv.z; a2.w += s2 * wv.w;
            a3.x += s3 * wv.x; a3.y += s3 * wv.y; a3.z += s3 * wv.z; a3.w += s3 * wv.w;
        }
    }
    // store 4 rows x 4 cols as bf16: one uint2 (8 B) per row
    uint2* S2 = (uint2*)Sb;                  // row stride = 32 uint2
    #define PACK2(f0, f1) (bf16_rne(f0) | (bf16_rne(f1) << 16))
    S2[(size_t)(row0 + 0) * 32 + cg] = make_uint2(PACK2(a0.x, a0.y), PACK2(a0.z, a0.w));
    S2[(size_t)(row0 + 1) * 32 + cg] = make_uint2(PACK2(a1.x, a1.y), PACK2(a1.z, a1.w));
    S2[(size_t)(row0 + 2) * 32 + cg] = make_uint2(PACK2(a2.x, a2.y), PACK2(a2.z, a2.w));
    S2[(size_t)(row0 + 3) * 32 + cg] = make_uint2(PACK2(a3.x, a3.y), PACK2(a3.z, a3.w));
    #undef PACK2
}

// ---------------------------------------------------------------------------
// CSR build step 1: histogram of edge rows (counts pre-zeroed).
// ---------------------------------------------------------------------------
__global__ void gc_hist(const int* __restrict__ er, int* __restrict__ counts) {
    int e = blockIdx.x * blockDim.x + threadIdx.x;
    if (e < N_EDGES) atomicAdd(&counts[er[e]], 1);
}

// ---------------------------------------------------------------------------
// Two-level scan: per-block local scan + block sums, scan sums, add-back.
// ---------------------------------------------------------------------------
__global__ __launch_bounds__(256) void gc_scan_a(const int* __restrict__ counts,
                                                 int* __restrict__ excl,
                                                 int* __restrict__ bsum) {
    __shared__ int sm[256];
    const int t = threadIdx.x;
    const int i = blockIdx.x * 256 + t;
    int c = (i < N_NODES) ? counts[i] : 0;
    sm[t] = c;
    __syncthreads();
    #pragma unroll
    for (int off = 1; off < 256; off <<= 1) {
        int v = (t >= off) ? sm[t - off] : 0;
        __syncthreads();
        sm[t] += v;
        __syncthreads();
    }
    if (i < N_NODES) excl[i] = sm[t] - c;
    if (t == 255) bsum[blockIdx.x] = sm[255];
}

__global__ __launch_bounds__(256) void gc_scan_b(const int* __restrict__ bsum,
                                                 int* __restrict__ bpre) {
    __shared__ int sm[256];
    const int t = threadIdx.x;
    int v = (t < SCAN_NBLK) ? bsum[t] : 0;
    sm[t] = v;
    __syncthreads();
    #pragma unroll
    for (int off = 1; off < 256; off <<= 1) {
        int x = (t >= off) ? sm[t - off] : 0;
        __syncthreads();
        sm[t] += x;
        __syncthreads();
    }
    if (t < SCAN_NBLK) bpre[t] = sm[t] - v;
}

__global__ __launch_bounds__(256) void gc_scan_c(const int* __restrict__ excl,
                                                 const int* __restrict__ bpre,
                                                 int* __restrict__ offsets,
                                                 int* __restrict__ cursor) {
    const int i = blockIdx.x * 256 + threadIdx.x;
    if (i < N_NODES) {
        int o = excl[i] + bpre[blockIdx.x];
        offsets[i] = o;
        cursor[i]  = o;
    }
    if (i == 0) offsets[N_NODES] = N_EDGES;
}

// ---------------------------------------------------------------------------
// CSR build step 3: scatter packed (col<<16 | bf16(val)) into row-sorted slots.
// ---------------------------------------------------------------------------
__global__ void gc_fill(const int* __restrict__ er, const int* __restrict__ ec,
                        const float* __restrict__ ev, int* __restrict__ cursor,
                        unsigned* __restrict__ csr) {
    int e = blockIdx.x * blockDim.x + threadIdx.x;
    if (e >= N_EDGES) return;
    int pos = atomicAdd(&cursor[er[e]], 1);
    csr[pos] = ((unsigned)ec[e] << 16) | bf16_rne(ev[e]);
}

// ---------------------------------------------------------------------------
// Gather: one wave per output row, lane owns 2 cols (one uint = 2 bf16).
// out[row] = bias + sum_e val_e * S[col_e].  256 B per edge per wave.
// ---------------------------------------------------------------------------
__global__ void gc_gather(const unsigned* __restrict__ Sb,
                          const int* __restrict__ offsets,
                          const unsigned* __restrict__ csr,
                          const float* __restrict__ bias,
                          float* __restrict__ out) {
    int wid  = (blockIdx.x * blockDim.x + threadIdx.x) >> 6;
    int lane = threadIdx.x & 63;
    if (wid >= N_NODES) return;

    int start = offsets[wid];
    int end   = offsets[wid + 1];

    float ax0 = 0.f, ay0 = 0.f, ax1 = 0.f, ay1 = 0.f;
    int e = start;
    for (; e + 3 < end; e += 4) {
        unsigned cv0 = csr[e];
        unsigned cv1 = csr[e + 1];
        unsigned cv2 = csr[e + 2];
        unsigned cv3 = csr[e + 3];
        unsigned s0 = Sb[(size_t)(cv0 >> 16) * 64 + lane];
        unsigned s1 = Sb[(size_t)(cv1 >> 16) * 64 + lane];
        unsigned s2 = Sb[(size_t)(cv2 >> 16) * 64 + lane];
        unsigned s3 = Sb[(size_t)(cv3 >> 16) * 64 + lane];
        float v0 = __uint_as_float(cv0 << 16);
        float v1 = __uint_as_float(cv1 << 16);
        float v2 = __uint_as_float(cv2 << 16);
        float v3 = __uint_as_float(cv3 << 16);
        ax0 += v0 * __uint_as_float(s0 << 16);
        ay0 += v0 * __uint_as_float(s0 & 0xffff0000u);
        ax1 += v1 * __uint_as_float(s1 << 16);
        ay1 += v1 * __uint_as_float(s1 & 0xffff0000u);
        ax0 += v2 * __uint_as_float(s2 << 16);
        ay0 += v2 * __uint_as_float(s2 & 0xffff0000u);
        ax1 += v3 * __uint_as_float(s3 << 16);
        ay1 += v3 * __uint_as_float(s3 & 0xffff0000u);
    }
    for (; e < end; ++e) {
        unsigned cv = csr[e];
        unsigned s = Sb[(size_t)(cv >> 16) * 64 + lane];
        float v = __uint_as_float(cv << 16);
        ax0 += v * __uint_as_float(s << 16);
        ay0 += v * __uint_as_float(s & 0xffff0000u);
    }

    float2 b = *(const float2*)(bias + lane * 2);
    float2 r = make_float2(ax0 + ax1 + b.x, ay0 + ay1 + b.y);
    *(float2*)(out + (size_t)wid * D + lane * 2) = r;
}

// ---------------------------------------------------------------------------
extern "C" void kernel_launch(void* const* d_in, const int* in_sizes, int n_in,
                              void* d_out, int out_size, void* d_ws, size_t ws_size,
                              hipStream_t stream) {
    const float* X    = (const float*)d_in[0];
    const float* W    = (const float*)d_in[1];
    const float* bias = (const float*)d_in[2];
    const float* ev   = (const float*)d_in[3];
    const int*   er   = (const int*)  d_in[4];
    const int*   ec   = (const int*)  d_in[5];
    float* out = (float*)d_out;

    char* ws = (char*)d_ws;
    unsigned* Sb      = (unsigned*)(ws + S_OFF);
    int*      counts  = (int*)(ws + COUNTS_OFF);
    int*      offsets = (int*)(ws + OFFS_OFF);
    int*      cursor  = (int*)(ws + CURSOR_OFF);
    int*      excl    = (int*)(ws + EXCL_OFF);
    int*      bsum    = (int*)(ws + BSUM_OFF);
    int*      bpre    = (int*)(ws + BPRE_OFF);
    unsigned* csr     = (unsigned*)(ws + CSR_OFF);

    // GEMM (64 rows / 512-thread block), bf16 output
    gc_gemm<<<(N_NODES + 63) / 64, 512, 0, stream>>>(X, W, Sb);

    hipMemsetAsync(counts, 0, N_NODES * sizeof(int), stream);

    int eblocks = (N_EDGES + 255) / 256;
    gc_hist<<<eblocks, 256, 0, stream>>>(er, counts);
    gc_scan_a<<<SCAN_NBLK, 256, 0, stream>>>(counts, excl, bsum);
    gc_scan_b<<<1, 256, 0, stream>>>(bsum, bpre);
    gc_scan_c<<<SCAN_NBLK, 256, 0, stream>>>(excl, bpre, offsets, cursor);
    gc_fill<<<eblocks, 256, 0, stream>>>(er, ec, ev, cursor, csr);

    // one wave per row: 50000 waves, 4 waves / 256-thread block
    int gblocks = (N_NODES * 64 + 255) / 256;
    gc_gather<<<gblocks, 256, 0, stream>>>(Sb, offsets, csr, bias, out);
}